// Round 1
// baseline (255.838 us; speedup 1.0000x reference)
//
#include <hip/hip_runtime.h>

#define DD 256
#define BB 512
#define NL 2048            // e-quantization LUT entries

// workspace layout (float offsets)
#define OFF_PART 0         // 512*4 floats: per-image fc1 partial contributions

typedef float v2f __attribute__((ext_vector_type(2)));

__device__ __forceinline__ v2f mk2(float a, float b) { v2f r; r.x = a; r.y = b; return r; }

__device__ __forceinline__ v2f fma2(v2f a, v2f b, v2f c) {
#if __has_builtin(__builtin_elementwise_fma)
  return __builtin_elementwise_fma(a, b, c);   // -> v_pk_fma_f32
#else
  return mk2(fmaf(a.x, b.x, c.x), fmaf(a.y, b.y, c.y));
#endif
}

__device__ __forceinline__ float wave_red(float v) {
#pragma unroll
  for (int off = 32; off > 0; off >>= 1) v += __shfl_down(v, off, 64);
  return v;
}

// async global->LDS, 16B per lane; LDS dest is wave-uniform base + lane*16
__device__ __forceinline__ void glds16(const float* src, float* lds_dst) {
  __builtin_amdgcn_global_load_lds(
      (const __attribute__((address_space(1))) unsigned int*)src,
      (__attribute__((address_space(3))) unsigned int*)lds_dst, 16, 0, 0);
}

// ---- fused: per-image sums + PWL tables + conv + fc1 partials ----
__global__ __launch_bounds__(1024, 4) void fused_kernel(
    const float* __restrict__ x, const float* __restrict__ w1,
    const float* __restrict__ b1, const float* __restrict__ w2,
    const float* __restrict__ b2p, const float* __restrict__ fc1w,
    float* __restrict__ ws) {
  const int b = blockIdx.x;          // one block per image
  const int tid = threadIdx.x;
  const int w = tid >> 6;            // wave 0..15
  const int lane = tid & 63;

  __shared__ __align__(16) float stage[16 * 2 * DD];   // 16 waves x 2 row-bufs (32 KB)
  __shared__ __align__(16) float tabP[264];
  __shared__ float rs_s[DD];
  __shared__ float cs_s[DD];
  __shared__ __align__(16) float wkA[DD][4];
  __shared__ unsigned short lut_s[NL];
  __shared__ __align__(16) float csl[16][DD];
  __shared__ float segsum_s[4][4];
  __shared__ float red_s[64];

  // early fc1-weight loads (complete while tables/sums run)
  float wk0 = 0.f, wk1 = 0.f, wk2 = 0.f, wk3 = 0.f;
  if (tid < 256) {
    wk0 = fc1w[0 * (BB * DD) + b * DD + tid];
    wk1 = fc1w[1 * (BB * DD) + b * DD + tid];
    wk2 = fc1w[2 * (BB * DD) + b * DD + tid];
    wk3 = fc1w[3 * (BB * DD) + b * DD + tid];
  }

  // ---- per-block PWL table build (w1/b1/w2 tiny, uniform scalar loads) ----
  {
    float w1v[10], b1v[10], bp[10];
#pragma unroll
    for (int c = 0; c < 10; ++c) { w1v[c] = w1[c]; b1v[c] = b1[c]; bp[c] = -b1v[c] / w1v[c]; }
    float lo = bp[0], hi = bp[0];
#pragma unroll
    for (int c = 1; c < 10; ++c) { lo = fminf(lo, bp[c]); hi = fmaxf(hi, bp[c]); }
    const float step = (hi - lo) / (float)(NL - 3);
    if (tid < 99) {
      int rank[10];
#pragma unroll
      for (int c = 0; c < 10; ++c) {
        int r = 0;
#pragma unroll
        for (int k = 0; k < 10; ++k)
          r += (bp[k] < bp[c] || (bp[k] == bp[c] && k < c)) ? 1 : 0;
        rank[c] = r;
      }
      const int s = tid / 9, tt = tid % 9;   // tt = dr*3 + kc
      const int dr = tt / 3, kc = tt % 3;
      float A = 0.f, Bv = 0.f;
#pragma unroll
      for (int c = 0; c < 10; ++c) {
        bool act = (w1v[c] > 0.f) ? (rank[c] < s)
                 : ((w1v[c] < 0.f) ? (rank[c] >= s) : (b1v[c] > 0.f));
        if (act) { A += w1v[c] * w2[c * 9 + tt]; Bv += b1v[c] * w2[c * 9 + tt]; }
      }
      const int base = (s * 3 + kc) * 8;
      const int posA = (dr == 2) ? 4 : dr;
      const int posB = (dr == 2) ? 5 : (2 + dr);
      tabP[base + posA] = A;
      tabP[base + posB] = Bv;
      tabP[base + 6] = 0.f;
      tabP[base + 7] = 0.f;
    }
    for (int k = tid; k < NL; k += 1024) {   // cell k left edge x = lo + (k-1)*step
      const float xx = lo + (float)(k - 1) * step;
      int s = 0;
#pragma unroll
      for (int c = 0; c < 10; ++c) s += (bp[c] < xx) ? 1 : 0;
      lut_s[k] = (unsigned short)(s * 96);
    }
  }

  // ---- streaming row/col sums via global_load_lds, wave-private double buffer ----
  {
    float* mystage = &stage[w * (2 * DD)];               // 2 bufs x 256 floats
    const float* gx = x + ((size_t)b << 16) + (size_t)(w * 16) * DD;
    glds16(gx + 0 * DD + lane * 4, mystage + 0);         // row 0 -> buf0
    glds16(gx + 1 * DD + lane * 4, mystage + DD);        // row 1 -> buf1
    float4 cacc = make_float4(0.f, 0.f, 0.f, 0.f);
#pragma unroll
    for (int r = 0; r < 16; ++r) {
      if (r < 15) asm volatile("s_waitcnt vmcnt(1)" ::: "memory");
      else        asm volatile("s_waitcnt vmcnt(0)" ::: "memory");
      __builtin_amdgcn_sched_barrier(0);
      const float4 v = ((const float4*)(mystage + (r & 1) * DD))[lane];
      cacc.x += v.x; cacc.y += v.y; cacc.z += v.z; cacc.w += v.w;
      float rsum = (v.x + v.y) + (v.z + v.w);
      __builtin_amdgcn_sched_barrier(0);                 // buf consumed before refill
      if (r + 2 < 16)
        glds16(gx + (r + 2) * DD + lane * 4, mystage + (r & 1) * DD);
      rsum = wave_red(rsum);
      if (lane == 0) rs_s[w * 16 + r] = rsum;
    }
    ((float4*)csl[w])[lane] = cacc;
    if (tid < 256) { wkA[tid][0] = wk0; wkA[tid][1] = wk1; wkA[tid][2] = wk2; wkA[tid][3] = wk3; }
  }
  __syncthreads();
  if (tid < 256) {
    float s0 = 0.f;
#pragma unroll
    for (int q = 0; q < 16; ++q) s0 += csl[q][tid];
    cs_s[tid] = s0;
  } else if (tid < 272) {
    const int t = tid - 256;
    const int ss = t >> 2, k = t & 3;
    float s = 0.f;
#pragma unroll
    for (int r = 0; r < 64; ++r) s += wkA[ss * 64 + r][k];
    segsum_s[ss][k] = s;
  }
  __syncthreads();

  // ---- conv phase (verbatim logic from verified kernel) ----
  const int seg = w >> 2;            // row segment
  const int wb = (w - seg) & 3;      // column band (anti-diagonal balance)
  const int j = wb * 64 + lane;
  const int jmin = wb * 64;
  const int r0 = seg * 64, r1 = r0 + 64;

  const float inv_step_c = [] __device__ () { return 0.f; }();  // placeholder removed below
  (void)inv_step_c;
  // recompute uniform PWL params (cheap, avoids extra LDS round trip)
  float lo_c, hi_c;
  {
    float bp0[10];
#pragma unroll
    for (int c = 0; c < 10; ++c) bp0[c] = -b1[c] / w1[c];
    lo_c = bp0[0]; hi_c = bp0[0];
#pragma unroll
    for (int c = 1; c < 10; ++c) { lo_c = fminf(lo_c, bp0[c]); hi_c = fmaxf(hi_c, bp0[c]); }
  }
  const float inv_step = (float)(NL - 3) / (hi_c - lo_c);
  const float bias = 1.0f - lo_c * inv_step;
  const float b2v = b2p[0];
  const float yb = fmaxf(b2v, 0.f);
  const float fxmax = (float)(NL - 1);

  float csr[3], vf[3];
  csr[0] = (j >= 1) ? cs_s[j - 1] : 0.f;
  csr[1] = cs_s[j];
  csr[2] = (j < DD - 1) ? cs_s[j + 1] : 0.f;
  vf[0] = (j >= 1) ? 1.f : 0.f;
  vf[1] = 1.f;
  vf[2] = (j < DD - 1) ? 1.f : 0.f;
  v2f vf2[3];
#pragma unroll
  for (int kc = 0; kc < 3; ++kc) vf2[kc] = mk2(vf[kc], vf[kc]);

  const int nt = min(max(jmin - 2 - r0, 0), 64);   // wave-trivial output rows
  const int rfirst = r0 + nt;
  const int iend = (r1 == DD) ? DD - 1 : r1;

  float P = 0.f, Q = 0.f;
  float vcol = 64.f * yb;                          // closed form yb contribution
  v2f a01 = mk2(yb * segsum_s[seg][0], yb * segsum_s[seg][1]);
  v2f a23 = mk2(yb * segsum_s[seg][2], yb * segsum_s[seg][3]);

#define TAP_CORE(KC, E, M2, MS)                                              \
  {                                                                          \
    float fx = fmaf((E), inv_step, bias);                                    \
    fx = fminf(fmaxf(fx, 0.f), fxmax);                                       \
    const int off = (int)lut_s[(int)fx];                                     \
    const char* tp = (const char*)tabP + (off + (KC) * 32);                  \
    const float4 ab = *(const float4*)tp;         /* A0,A1,B0,B1 */          \
    const float2 ab2 = *(const float2*)(tp + 16); /* A2,B2 */                \
    v2f tv = fma2(mk2(ab.x, ab.y), mk2((E), (E)), mk2(ab.z, ab.w));          \
    R01 = fma2((M2), tv, R01);                                               \
    R2 = fmaf((MS), fmaf(ab2.x, (E), ab2.y), R2);                            \
  }

  if (rfirst < r1) {
    if (seg > wb) {
      // ---- 2 guarded warmup iters (no finalize): i = r0-1, r0 ----
      for (int i = r0 - 1; i <= r0; ++i) {
        const float rsv = rs_s[i];
        v2f R01 = mk2(0.f, 0.f); float R2 = 0.f;
#pragma unroll
        for (int kc = 0; kc < 3; ++kc) {
          const float e = rsv + csr[kc];
          const float m = ((j - 1 + kc) <= i) ? vf[kc] : 0.f;
          TAP_CORE(kc, e, mk2(m, m), m)
        }
        P = Q + R01.y; Q = R01.x;
      }
      // ---- interior loop: all lanes in-tril, finalize every iter ----
      for (int i = r0 + 1; i <= iend; ++i) {
        const float rsv = rs_s[i];
        v2f R01 = mk2(0.f, 0.f); float R2 = 0.f;
#pragma unroll
        for (int kc = 0; kc < 3; ++kc) {
          const float e = rsv + csr[kc];
          TAP_CORE(kc, e, vf2[kc], vf[kc])
        }
        const float yd = fmaxf(P + R2 + b2v, 0.f) - yb;
        vcol += yd;
        const float4 wkv = *(const float4*)wkA[i - 1];
        a01 = fma2(mk2(yd, yd), mk2(wkv.x, wkv.y), a01);
        a23 = fma2(mk2(yd, yd), mk2(wkv.z, wkv.w), a23);
        P = Q + R01.y; Q = R01.x;
      }
    } else {
      // ---- guarded loop (diagonal / near-trivial waves) ----
      const int ibeg = (nt > 0) ? rfirst - 1 : ((r0 == 0) ? 0 : r0 - 1);
      const int ffrom = rfirst + 1;
      for (int i = ibeg; i <= iend; ++i) {
        const float rsv = rs_s[i];
        v2f R01 = mk2(0.f, 0.f); float R2 = 0.f;
        if (j - 1 <= i) {
#pragma unroll
          for (int kc = 0; kc < 3; ++kc) {
            const float e = rsv + csr[kc];
            const float m = ((j - 1 + kc) <= i) ? vf[kc] : 0.f;
            TAP_CORE(kc, e, mk2(m, m), m)
          }
        }
        if (i >= ffrom) {
          const float yd = fmaxf(P + R2 + b2v, 0.f) - yb;
          vcol += yd;
          const float4 wkv = *(const float4*)wkA[i - 1];
          a01 = fma2(mk2(yd, yd), mk2(wkv.x, wkv.y), a01);
          a23 = fma2(mk2(yd, yd), mk2(wkv.z, wkv.w), a23);
        }
        P = Q + R01.y; Q = R01.x;
      }
    }
  }
  if (r1 == DD) {                    // flush output row 255
    const float yd = fmaxf(P + b2v, 0.f) - yb;
    vcol += yd;
    const float4 wkv = *(const float4*)wkA[DD - 1];
    a01 = fma2(mk2(yd, yd), mk2(wkv.x, wkv.y), a01);
    a23 = fma2(mk2(yd, yd), mk2(wkv.z, wkv.w), a23);
  }

  // column-sum term: vcol * Wk[b, j]
  const float4 wkj = *(const float4*)wkA[j];
  a01 = fma2(mk2(vcol, vcol), mk2(wkj.x, wkj.y), a01);
  a23 = fma2(mk2(vcol, vcol), mk2(wkj.z, wkj.w), a23);

  float acc0 = wave_red(a01.x), acc1 = wave_red(a01.y);
  float acc2 = wave_red(a23.x), acc3 = wave_red(a23.y);
  if (lane == 0) {
    red_s[w * 4 + 0] = acc0; red_s[w * 4 + 1] = acc1;
    red_s[w * 4 + 2] = acc2; red_s[w * 4 + 3] = acc3;
  }
  __syncthreads();
  if (tid < 4) {
    float s = 0.f;
#pragma unroll
    for (int wv = 0; wv < 16; ++wv) s += red_s[wv * 4 + tid];
    ws[OFF_PART + b * 4 + tid] = s;   // plain store: no init, no atomics
  }
#undef TAP_CORE
}

// ---- K2: reduce per-image partials -> relu(fc1) -> fc2 -> 2 outputs ----
__global__ void fc_kernel(const float* __restrict__ fc1b, const float* __restrict__ fc2w,
                          const float* __restrict__ fc2b, const float* __restrict__ ws,
                          float* __restrict__ out) {
  const int tid = threadIdx.x;       // 256 threads: wave k owns hfc[k]
  const int k = tid >> 6, lane = tid & 63;
  __shared__ float hfc_s[4];
  float s = 0.f;
#pragma unroll
  for (int m = 0; m < 8; ++m) s += ws[OFF_PART + (lane + m * 64) * 4 + k];
  s = wave_red(s);
  if (lane == 0) hfc_s[k] = s;
  __syncthreads();
  if (tid == 0) {
    float o0 = fc2b[0], o1 = fc2b[1];
#pragma unroll
    for (int kk = 0; kk < 4; ++kk) {
      float h = fmaxf(hfc_s[kk] + fc1b[kk], 0.f);
      o0 += fc2w[kk] * h;
      o1 += fc2w[4 + kk] * h;
    }
    out[0] = o0; out[1] = o1;
  }
}

extern "C" void kernel_launch(void* const* d_in, const int* in_sizes, int n_in,
                              void* d_out, int out_size, void* d_ws, size_t ws_size,
                              hipStream_t stream) {
  const float* x    = (const float*)d_in[0];
  const float* w1   = (const float*)d_in[1];
  const float* b1   = (const float*)d_in[2];
  const float* w2   = (const float*)d_in[3];
  const float* b2   = (const float*)d_in[4];
  const float* fc1w = (const float*)d_in[5];
  const float* fc1b = (const float*)d_in[6];
  const float* fc2w = (const float*)d_in[7];
  const float* fc2b = (const float*)d_in[8];
  float* out = (float*)d_out;
  float* ws  = (float*)d_ws;

  hipLaunchKernelGGL(fused_kernel, dim3(512), dim3(1024), 0, stream,
                     x, w1, b1, w2, b2, fc1w, ws);
  hipLaunchKernelGGL(fc_kernel, dim3(1), dim3(256), 0, stream,
                     fc1b, fc2w, fc2b, ws, out);
}

// Round 2
// 239.659 us; speedup vs baseline: 1.0675x; 1.0675x over previous
//
#include <hip/hip_runtime.h>

#define DD 256
#define BB 512
#define NL 2048            // e-quantization LUT entries

// workspace layout (float offsets)
#define OFF_RS   0          // 512*256 row sums
#define OFF_CSP  131072     // 2048*256 col-sum partials (4 per batch)
#define OFF_HFC  655360     // 4 fc1 pre-activations
#define OFF_PAR  655368     // inv_step, bias
#define OFF_TABP 655376     // 33 rows * 8 floats: (s*3+kc)*8 -> A0,A1,B0,B1,A2,B2,_,_
#define OFF_LUT  655648     // 2048 u16: quantized e -> s*96 byte offset

typedef float v2f __attribute__((ext_vector_type(2)));

__device__ __forceinline__ v2f mk2(float a, float b) { v2f r; r.x = a; r.y = b; return r; }

__device__ __forceinline__ v2f fma2(v2f a, v2f b, v2f c) {
#if __has_builtin(__builtin_elementwise_fma)
  return __builtin_elementwise_fma(a, b, c);   // -> v_pk_fma_f32
#else
  return mk2(fmaf(a.x, b.x, c.x), fmaf(a.y, b.y, c.y));
#endif
}

__device__ __forceinline__ float wave_red(float v) {
#pragma unroll
  for (int off = 32; off > 0; off >>= 1) v += __shfl_down(v, off, 64);
  return v;
}

// ---- K1: row sums + col-sum partials; block 2048 builds PWL tables + LUT ----
__global__ __launch_bounds__(256) void sum_kernel(const float* __restrict__ x,
                                                  const float* __restrict__ w1,
                                                  const float* __restrict__ b1,
                                                  const float* __restrict__ w2,
                                                  float* __restrict__ ws) {
  const int bq = blockIdx.x;
  const int tid = threadIdx.x;
  if (bq == 2048) {                  // ---- table-builder block ----
    const int t = tid;
    float w1v[10], b1v[10], bp[10];
    int rank[10];
#pragma unroll
    for (int c = 0; c < 10; ++c) { w1v[c] = w1[c]; b1v[c] = b1[c]; bp[c] = -b1v[c] / w1v[c]; }
#pragma unroll
    for (int c = 0; c < 10; ++c) {
      int r = 0;
#pragma unroll
      for (int k = 0; k < 10; ++k)
        r += (bp[k] < bp[c] || (bp[k] == bp[c] && k < c)) ? 1 : 0;
      rank[c] = r;
    }
    float lo = bp[0], hi = bp[0];
#pragma unroll
    for (int c = 1; c < 10; ++c) { lo = fminf(lo, bp[c]); hi = fmaxf(hi, bp[c]); }
    const float step = (hi - lo) / (float)(NL - 3);
    if (t == 0) {
      ws[OFF_PAR]     = (float)(NL - 3) / (hi - lo);
      ws[OFF_PAR + 1] = 1.0f - lo * ((float)(NL - 3) / (hi - lo));
    }
    if (t < 99) {
      const int s = t / 9, tt = t % 9;    // tt = dr*3 + kc
      const int dr = tt / 3, kc = tt % 3;
      float A = 0.f, Bv = 0.f;
      for (int c = 0; c < 10; ++c) {
        bool act = (w1v[c] > 0.f) ? (rank[c] < s)
                 : ((w1v[c] < 0.f) ? (rank[c] >= s) : (b1v[c] > 0.f));
        if (act) { A += w1v[c] * w2[c * 9 + tt]; Bv += b1v[c] * w2[c * 9 + tt]; }
      }
      const int base = (s * 3 + kc) * 8;
      const int posA = (dr == 2) ? 4 : dr;
      const int posB = (dr == 2) ? 5 : (2 + dr);
      ws[OFF_TABP + base + posA] = A;
      ws[OFF_TABP + base + posB] = Bv;
      ws[OFF_TABP + base + 6] = 0.f;
      ws[OFF_TABP + base + 7] = 0.f;
    }
    unsigned short* lut = (unsigned short*)(ws + OFF_LUT);
    for (int k = t; k < NL; k += 256) {   // cell k left edge x = lo + (k-1)*step
      const float xx = lo + (float)(k - 1) * step;
      int s = 0;
#pragma unroll
      for (int c = 0; c < 10; ++c) s += (bp[c] < xx) ? 1 : 0;
      lut[k] = (unsigned short)(s * 96);
    }
    return;
  }
  // ---- streaming sum block ----
  const int b = bq >> 2;
  const int q = bq & 3;
  const int lane = tid & 63;
  const int wv = tid >> 6;
  __shared__ float rowp[64][65];
  __shared__ float csl[4][DD];
  __shared__ float segp[4][64];
  float4 cacc = make_float4(0.f, 0.f, 0.f, 0.f);
  const float4* px = (const float4*)(x + ((size_t)b << 16) + ((size_t)(q * 64 + wv * 16) << 8));
#pragma unroll
  for (int r = 0; r < 16; ++r) {
    float4 val = px[r * 64 + lane];
    cacc.x += val.x; cacc.y += val.y; cacc.z += val.z; cacc.w += val.w;
    rowp[wv * 16 + r][lane] = (val.x + val.y) + (val.z + val.w);
  }
  ((float4*)csl[wv])[lane] = cacc;
  __syncthreads();
  {
    const int row = tid & 63, seg = tid >> 6;
    const float* rp = rowp[row] + seg * 16;
    float s = 0.f;
#pragma unroll
    for (int k = 0; k < 16; ++k) s += rp[k];
    segp[seg][row] = s;
  }
  __syncthreads();
  if (tid < 64)
    ws[OFF_RS + b * DD + q * 64 + tid] =
        (segp[0][tid] + segp[1][tid]) + (segp[2][tid] + segp[3][tid]);
  ws[OFF_CSP + bq * DD + tid] =
      (csl[0][tid] + csl[1][tid]) + (csl[2][tid] + csl[3][tid]);
  if (bq == 0 && tid < 4) ws[OFF_HFC + tid] = 0.f;
}

// ---- K2: one block/image; LUT lookup; packed fp32; load-balanced wave map ----
__global__ __launch_bounds__(1024, 8) void conv_kernel(const float* __restrict__ b2p,
                                                       const float* __restrict__ fc1w,
                                                       float* __restrict__ ws) {
  const int b = blockIdx.x;          // 512 blocks
  const int tid = threadIdx.x;
  const int w = tid >> 6;            // wave 0..15
  const int lane = tid & 63;

  // load-balanced wave -> (column band, output-row run) map.
  // band wb covers columns [64*wb, 64*wb+64); non-trivial outputs are rows
  // >= 64*wb - 2 (spans 256/194/130/66), split into 6/5/3/2 runs (max 44 rows).
  int wb, r0, r1;
  switch (w) {
    case 0:  wb = 0; r0 = 0;   r1 = 43;  break;
    case 1:  wb = 0; r0 = 43;  r1 = 86;  break;
    case 2:  wb = 0; r0 = 86;  r1 = 129; break;
    case 3:  wb = 0; r0 = 129; r1 = 172; break;
    case 4:  wb = 0; r0 = 172; r1 = 214; break;
    case 5:  wb = 0; r0 = 214; r1 = 256; break;
    case 6:  wb = 1; r0 = 62;  r1 = 101; break;
    case 7:  wb = 1; r0 = 101; r1 = 140; break;
    case 8:  wb = 1; r0 = 140; r1 = 179; break;
    case 9:  wb = 1; r0 = 179; r1 = 218; break;
    case 10: wb = 1; r0 = 218; r1 = 256; break;
    case 11: wb = 2; r0 = 126; r1 = 170; break;
    case 12: wb = 2; r0 = 170; r1 = 213; break;
    case 13: wb = 2; r0 = 213; r1 = 256; break;
    case 14: wb = 3; r0 = 190; r1 = 223; break;
    default: wb = 3; r0 = 223; r1 = 256; break;
  }
  const int jmin = wb * 64;
  const int j = jmin + lane;

  __shared__ __align__(16) float tabP[264];
  __shared__ float rs_s[DD];
  __shared__ float cs_s[DD];
  __shared__ __align__(16) float wkA[DD][4];
  __shared__ unsigned short lut_s[NL];
  __shared__ float segsum_s[4][4];
  __shared__ float red_s[64];

  // ---- preamble ----
  ((unsigned int*)lut_s)[tid] = ((const unsigned int*)(ws + OFF_LUT))[tid];
  if (tid < 256) {
    rs_s[tid] = ws[OFF_RS + b * DD + tid];
  } else if (tid < 512) {
    const int t = tid - 256;
    const float* csp = ws + OFF_CSP + (b * 4) * DD + t;
    cs_s[t] = (csp[0] + csp[DD]) + (csp[2 * DD] + csp[3 * DD]);
  } else if (tid < 768) {
    const int r = tid - 512;
#pragma unroll
    for (int k = 0; k < 4; ++k) wkA[r][k] = fc1w[k * (BB * DD) + b * DD + r];
  } else {
    const int u = tid - 768;
    if (u < 256) tabP[u] = ws[OFF_TABP + u];
  }
  if (tid < 8) tabP[256 + tid] = ws[OFF_TABP + 256 + tid];
  __syncthreads();
  if (tid < 16) {
    const int ss = tid >> 2, k = tid & 3;
    float s = 0.f;
#pragma unroll
    for (int r = 0; r < 64; ++r) s += wkA[ss * 64 + r][k];
    segsum_s[ss][k] = s;
  }
  __syncthreads();

  const float inv_step = ws[OFF_PAR];
  const float bias = ws[OFF_PAR + 1];
  const float b2v = b2p[0];
  const float yb = fmaxf(b2v, 0.f);
  const float fxmax = (float)(NL - 1);

  float csr[3], vf[3];
  csr[0] = (j >= 1) ? cs_s[j - 1] : 0.f;
  csr[1] = cs_s[j];
  csr[2] = (j < DD - 1) ? cs_s[j + 1] : 0.f;
  vf[0] = (j >= 1) ? 1.f : 0.f;
  vf[1] = 1.f;
  vf[2] = (j < DD - 1) ? 1.f : 0.f;
  v2f vf2[3];
#pragma unroll
  for (int kc = 0; kc < 3; ++kc) vf2[kc] = mk2(vf[kc], vf[kc]);

  const int dlim = jmin + 63;                      // last input row needing masks
  const int iend = (r1 == DD) ? DD - 1 : r1;

  float P = 0.f, Q = 0.f;
  float vcol = 0.f;                                // yd-only; yb baseline closed-form
  v2f a01 = mk2(0.f, 0.f);
  v2f a23 = mk2(0.f, 0.f);

#define TAP_CORE(KC, E, M2, MS)                                              \
  {                                                                          \
    float fx = fmaf((E), inv_step, bias);                                    \
    fx = fminf(fmaxf(fx, 0.f), fxmax);                                       \
    const int off = (int)lut_s[(int)fx];                                     \
    const char* tp = (const char*)tabP + (off + (KC) * 32);                  \
    const float4 ab = *(const float4*)tp;         /* A0,A1,B0,B1 */          \
    const float2 ab2 = *(const float2*)(tp + 16); /* A2,B2 */                \
    v2f tv = fma2(mk2(ab.x, ab.y), mk2((E), (E)), mk2(ab.z, ab.w));          \
    R01 = fma2((M2), tv, R01);                                               \
    R2 = fmaf((MS), fmaf(ab2.x, (E), ab2.y), R2);                            \
  }

  if (r0 >= dlim) {
    // ---- interior-class run: 2 masked warmups (no finalize), then fast loop ----
    for (int i = r0 - 1; i <= r0; ++i) {
      const float rsv = rs_s[i];
      v2f R01 = mk2(0.f, 0.f); float R2 = 0.f;
#pragma unroll
      for (int kc = 0; kc < 3; ++kc) {
        const float e = rsv + csr[kc];
        const float m = ((j - 1 + kc) <= i) ? vf[kc] : 0.f;
        TAP_CORE(kc, e, mk2(m, m), m)
      }
      (void)R2;
      P = Q + R01.y; Q = R01.x;
    }
    for (int i = r0 + 1; i <= iend; ++i) {
      const float rsv = rs_s[i];
      v2f R01 = mk2(0.f, 0.f); float R2 = 0.f;
#pragma unroll
      for (int kc = 0; kc < 3; ++kc) {
        const float e = rsv + csr[kc];
        TAP_CORE(kc, e, vf2[kc], vf[kc])
      }
      const float yd = fmaxf(P + R2 + b2v, 0.f) - yb;
      vcol += yd;
      const float4 wkv = *(const float4*)wkA[i - 1];
      a01 = fma2(mk2(yd, yd), mk2(wkv.x, wkv.y), a01);
      a23 = fma2(mk2(yd, yd), mk2(wkv.z, wkv.w), a23);
      P = Q + R01.y; Q = R01.x;
    }
  } else {
    // ---- diagonal-class run: guarded phase, then unmasked continuation ----
    const int ibeg = (r0 == 0) ? 0 : r0 - 1;
    const int ffrom = r0 + 1;
    const int gend = (iend < dlim) ? iend : dlim;
    for (int i = ibeg; i <= gend; ++i) {
      const float rsv = rs_s[i];
      v2f R01 = mk2(0.f, 0.f); float R2 = 0.f;
      if (j - 1 <= i) {
#pragma unroll
        for (int kc = 0; kc < 3; ++kc) {
          const float e = rsv + csr[kc];
          const float m = ((j - 1 + kc) <= i) ? vf[kc] : 0.f;
          TAP_CORE(kc, e, mk2(m, m), m)
        }
      }
      if (i >= ffrom) {
        const float yd = fmaxf(P + R2 + b2v, 0.f) - yb;
        vcol += yd;
        const float4 wkv = *(const float4*)wkA[i - 1];
        a01 = fma2(mk2(yd, yd), mk2(wkv.x, wkv.y), a01);
        a23 = fma2(mk2(yd, yd), mk2(wkv.z, wkv.w), a23);
      }
      P = Q + R01.y; Q = R01.x;
    }
    for (int i = dlim + 1; i <= iend; ++i) {
      const float rsv = rs_s[i];
      v2f R01 = mk2(0.f, 0.f); float R2 = 0.f;
#pragma unroll
      for (int kc = 0; kc < 3; ++kc) {
        const float e = rsv + csr[kc];
        TAP_CORE(kc, e, vf2[kc], vf[kc])
      }
      const float yd = fmaxf(P + R2 + b2v, 0.f) - yb;
      vcol += yd;
      const float4 wkv = *(const float4*)wkA[i - 1];
      a01 = fma2(mk2(yd, yd), mk2(wkv.x, wkv.y), a01);
      a23 = fma2(mk2(yd, yd), mk2(wkv.z, wkv.w), a23);
      P = Q + R01.y; Q = R01.x;
    }
  }
  if (r1 == DD) {                    // flush output row 255
    const float yd = fmaxf(P + b2v, 0.f) - yb;
    vcol += yd;
    const float4 wkv = *(const float4*)wkA[DD - 1];
    a01 = fma2(mk2(yd, yd), mk2(wkv.x, wkv.y), a01);
    a23 = fma2(mk2(yd, yd), mk2(wkv.z, wkv.w), a23);
  }

  // column-sum term: vcol * Wk[b, j]
  const float4 wkj = *(const float4*)wkA[j];
  a01 = fma2(mk2(vcol, vcol), mk2(wkj.x, wkj.y), a01);
  a23 = fma2(mk2(vcol, vcol), mk2(wkj.z, wkj.w), a23);

  float acc0 = wave_red(a01.x), acc1 = wave_red(a01.y);
  float acc2 = wave_red(a23.x), acc3 = wave_red(a23.y);
  if (lane == 0) {
    red_s[w * 4 + 0] = acc0; red_s[w * 4 + 1] = acc1;
    red_s[w * 4 + 2] = acc2; red_s[w * 4 + 3] = acc3;
  }
  __syncthreads();
  if (tid < 4) {
    float s = 0.f;
#pragma unroll
    for (int wv = 0; wv < 16; ++wv) s += red_s[wv * 4 + tid];
    // closed-form yb baseline: sum_{i,j} yb*(wk[i]+wk[j]) = 512*yb*sum_r wk[r]
    const float wt = (segsum_s[0][tid] + segsum_s[1][tid]) +
                     (segsum_s[2][tid] + segsum_s[3][tid]);
    s = fmaf(512.f * yb, wt, s);
    atomicAdd(&ws[OFF_HFC + tid], s);
  }
#undef TAP_CORE
}

// ---- K3: relu(fc1) -> fc2 -> 2 outputs ----
__global__ void fc_kernel(const float* __restrict__ fc1b, const float* __restrict__ fc2w,
                          const float* __restrict__ fc2b, const float* __restrict__ ws,
                          float* __restrict__ out) {
  if (threadIdx.x == 0 && blockIdx.x == 0) {
    float o0 = fc2b[0], o1 = fc2b[1];
#pragma unroll
    for (int k = 0; k < 4; ++k) {
      float h = fmaxf(ws[OFF_HFC + k] + fc1b[k], 0.f);
      o0 += fc2w[k] * h;
      o1 += fc2w[4 + k] * h;
    }
    out[0] = o0; out[1] = o1;
  }
}

extern "C" void kernel_launch(void* const* d_in, const int* in_sizes, int n_in,
                              void* d_out, int out_size, void* d_ws, size_t ws_size,
                              hipStream_t stream) {
  const float* x    = (const float*)d_in[0];
  const float* w1   = (const float*)d_in[1];
  const float* b1   = (const float*)d_in[2];
  const float* w2   = (const float*)d_in[3];
  const float* b2   = (const float*)d_in[4];
  const float* fc1w = (const float*)d_in[5];
  const float* fc1b = (const float*)d_in[6];
  const float* fc2w = (const float*)d_in[7];
  const float* fc2b = (const float*)d_in[8];
  float* out = (float*)d_out;
  float* ws  = (float*)d_ws;

  hipLaunchKernelGGL(sum_kernel,  dim3(2049), dim3(256), 0, stream, x, w1, b1, w2, ws);
  hipLaunchKernelGGL(conv_kernel, dim3(512), dim3(1024), 0, stream, b2, fc1w, ws);
  hipLaunchKernelGGL(fc_kernel,   dim3(1), dim3(64), 0, stream, fc1b, fc2w, fc2b, ws, out);
}